// Round 3
// baseline (7112.691 us; speedup 1.0000x reference)
//
#include <hip/hip_runtime.h>
#include <cstdint>
#include <cstddef>

// Rank1BayesianRNN on MI355X — round 3: fix seq batch-row stride
// (sA0 = T*D = 131072, was 65536 -> layer-0 x was scrambled for 255/256
// rows; explains the precision-independent 0.165 absmax in rounds 1-2).
// Otherwise identical to round 2: fp32 emulation via bf16 hi/lo 3-MFMA,
// per-ensemble folded weights (col-major, gate-interleaved), 257 phase
// launches (layer0 step t || layer1 step t-1), in-register LSTM cell.

typedef __attribute__((ext_vector_type(8))) short  s16x8;
typedef __attribute__((ext_vector_type(8))) __bf16 bf16x8;
typedef __attribute__((ext_vector_type(4))) float  f32x4;

__device__ __forceinline__ short f2bfs(float f) {
  union { float f; unsigned u; } v; v.f = f;
  unsigned r = v.u + 0x7FFFu + ((v.u >> 16) & 1u);   // RNE
  return (short)(r >> 16);
}
__device__ __forceinline__ float bf2f(short s) {
  union { unsigned u; float f; } v; v.u = ((unsigned)(unsigned short)s) << 16;
  return v.f;
}
// RNE hi + RNE residual lo: v ~= bf2f(hi) + bf2f(lo) to ~2^-18 rel.
__device__ __forceinline__ void split2(float v, short& hi, short& lo) {
  hi = f2bfs(v);
  lo = f2bfs(v - bf2f(hi));
}
__device__ __forceinline__ float sigf(float x) { return 1.0f / (1.0f + __expf(-x)); }

// ---------------------------------------------------------------------------
// GEMM body: 64 rows x 64 cols, K staged in 128-chunks x {hi,lo} planes in
// 64KB LDS (2 x 32KB ping-pong), XOR-swizzled. Per k-chunk: 3 MFMAs
// (ahi*bhi + alo*bhi + ahi*blo). A sources give bf16 hi/lo pairs, or fp32
// split on the fly (layer0 x). EPI: 0=LSTM cell, 1=relu6->hi/lo, 2=f32 out.
// ---------------------------------------------------------------------------
template<int EPI>
__device__ __forceinline__ void gemm_body(
    short* Bs,                                   // __shared__, 2*16384 shorts
    const float* a0f, const short* a0hi, const short* a0lo, long long sA0,
    const short* a1hi, const short* a1lo, long long sA1, int kSplit,
    const short* Wfe,                            // [64 cols][2 planes][K]
    const float* bias, int N, int K,
    int e, int cb, int rowBase,
    float* cbuf, const short* hinhi, const short* hinlo,
    short* houthi, short* houtlo, const int* slen, int step,
    short* outhi, short* outlo, float* outf)
{
  const int tid  = threadIdx.x;
  const int wave = tid >> 6, lane = tid & 63;
  const int nStages = K >> 7;
  const int rowg = rowBase + wave * 16 + (lane & 15);
  const int koff = (lane >> 4) << 3;
  const long long K2 = 2LL * K;

  s16x8 pre[8];
  // stage 0: load + LDS write + barrier
  #pragma unroll
  for (int i = 0; i < 8; ++i) {
    int f = tid + (i << 8);
    int p = f >> 10, r = (f >> 4) & 63, kc = (f & 15) << 3;
    pre[i] = *reinterpret_cast<const s16x8*>(Wfe + (size_t)r * K2 + (size_t)p * K + kc);
  }
  #pragma unroll
  for (int i = 0; i < 8; ++i) {
    int f = tid + (i << 8);
    int p = f >> 10, r = (f >> 4) & 63, kc = (f & 15) << 3;
    int byo = ((p << 14) | (((r << 7) + kc) << 1)) ^ ((r & 7) << 4);
    *reinterpret_cast<s16x8*>(reinterpret_cast<char*>(Bs) + byo) = pre[i];
  }
  __syncthreads();

  f32x4 acc[4] = {};

  for (int s = 0; s < nStages; ++s) {
    // issue next-stage B loads early (latency hides under MFMA)
    if (s + 1 < nStages) {
      const short* srcp = Wfe + ((s + 1) << 7);
      #pragma unroll
      for (int i = 0; i < 8; ++i) {
        int f = tid + (i << 8);
        int p = f >> 10, r = (f >> 4) & 63, kc = (f & 15) << 3;
        pre[i] = *reinterpret_cast<const s16x8*>(srcp + (size_t)r * K2 + (size_t)p * K + kc);
      }
    }
    const int  kb   = s << 7;
    const char* bsrc = reinterpret_cast<const char*>(Bs) + (s & 1) * 32768;
    const bool use0 = kb < kSplit;
    #pragma unroll
    for (int ks = 0; ks < 4; ++ks) {
      const int kloc = (ks << 5) + koff;
      const int kg   = kb + kloc;
      s16x8 ahi, alo;
      if (use0) {
        if (a0f != nullptr) {                    // fp32 source: split on the fly
          const float* p = a0f + (size_t)rowg * sA0 + kg;
          float4 x0 = *reinterpret_cast<const float4*>(p);
          float4 x1 = *reinterpret_cast<const float4*>(p + 4);
          float xv[8] = {x0.x, x0.y, x0.z, x0.w, x1.x, x1.y, x1.z, x1.w};
          #pragma unroll
          for (int j = 0; j < 8; ++j) {
            union { float f; unsigned u; } vv; vv.f = xv[j];
            short h = (short)(vv.u >> 16);       // truncate -> hi
            ahi[j] = h;
            alo[j] = f2bfs(xv[j] - bf2f(h));     // residual -> lo
          }
        } else {
          ahi = *reinterpret_cast<const s16x8*>(a0hi + (size_t)rowg * sA0 + kg);
          alo = *reinterpret_cast<const s16x8*>(a0lo + (size_t)rowg * sA0 + kg);
        }
      } else {
        ahi = *reinterpret_cast<const s16x8*>(a1hi + (size_t)rowg * sA1 + (kg - kSplit));
        alo = *reinterpret_cast<const s16x8*>(a1lo + (size_t)rowg * sA1 + (kg - kSplit));
      }
      #pragma unroll
      for (int cf = 0; cf < 4; ++cf) {
        const int ccol = (cf << 4) + (lane & 15);
        const int byoH = ((((ccol << 7) + kloc) << 1)) ^ ((ccol & 7) << 4);
        s16x8 bhi = *reinterpret_cast<const s16x8*>(bsrc + byoH);
        s16x8 blo = *reinterpret_cast<const s16x8*>(bsrc + (byoH | 16384));
        acc[cf] = __builtin_amdgcn_mfma_f32_16x16x32_bf16(
            __builtin_bit_cast(bf16x8, ahi), __builtin_bit_cast(bf16x8, bhi),
            acc[cf], 0, 0, 0);
        acc[cf] = __builtin_amdgcn_mfma_f32_16x16x32_bf16(
            __builtin_bit_cast(bf16x8, alo), __builtin_bit_cast(bf16x8, bhi),
            acc[cf], 0, 0, 0);
        acc[cf] = __builtin_amdgcn_mfma_f32_16x16x32_bf16(
            __builtin_bit_cast(bf16x8, ahi), __builtin_bit_cast(bf16x8, blo),
            acc[cf], 0, 0, 0);
      }
    }
    // write next-stage B to LDS (vmcnt wait lands here, after compute)
    if (s + 1 < nStages) {
      char* bdst = reinterpret_cast<char*>(Bs) + ((s + 1) & 1) * 32768;
      #pragma unroll
      for (int i = 0; i < 8; ++i) {
        int f = tid + (i << 8);
        int p = f >> 10, r = (f >> 4) & 63, kc = (f & 15) << 3;
        int byo = ((p << 14) | (((r << 7) + kc) << 1)) ^ ((r & 7) << 4);
        *reinterpret_cast<s16x8*>(bdst + byo) = pre[i];
      }
    }
    __syncthreads();
  }

  // ---- epilogue ----
  const int j = lane & 15;
  const int rbase = rowBase + wave * 16 + ((lane >> 4) << 2);
  if (EPI == 0) {
    // gate-interleaved cols: acc[0..3] = i,f,g,o for same (row, unit).
    const int u = (cb << 4) + j;                  // unit in [0,512)
    const float* bp = bias + (size_t)e * N + (cb << 6) + j;
    const float bi = bp[0], bff = bp[16], bg = bp[32], bo = bp[48];
    #pragma unroll
    for (int r = 0; r < 4; ++r) {
      const int row = rbase + r;
      const size_t idx = ((size_t)row << 9) + u;   // row*512 + u
      float zi = acc[0][r] + bi;
      float zf = acc[1][r] + bff;
      float zg = acc[2][r] + bg;
      float zo = acc[3][r] + bo;
      float cold = cbuf[idx];
      float cn = sigf(zf) * cold + sigf(zi) * tanhf(zg);
      float hn = sigf(zo) * tanhf(cn);
      short hh, hl;
      split2(hn, hh, hl);
      if (step >= slen[row]) {                     // masked: carry state
        cn = cold; hh = hinhi[idx]; hl = hinlo[idx];
      }
      cbuf[idx] = cn;
      houthi[idx] = hh;
      houtlo[idx] = hl;
    }
  } else {
    #pragma unroll
    for (int cf = 0; cf < 4; ++cf) {
      const int col = (cb << 6) + (cf << 4) + j;
      const float bb = bias[(size_t)e * N + col];
      #pragma unroll
      for (int r = 0; r < 4; ++r) {
        const int row = rbase + r;
        float z = acc[cf][r] + bb;
        if (EPI == 1) {
          z = fminf(fmaxf(z, 0.0f), 6.0f);
          short hh, hl; split2(z, hh, hl);
          outhi[(size_t)row * N + col] = hh;
          outlo[(size_t)row * N + col] = hl;
        } else {
          outf[(size_t)row * N + col] = z;
        }
      }
    }
  }
}

// ---------------------------------------------------------------------------
// Phase kernel: z=0 -> layer0 step t ; z=1 -> layer1 step t-1 (independent).
// ---------------------------------------------------------------------------
__global__ __launch_bounds__(256) void lstm_phase(
    const float* __restrict__ seq,
    short* __restrict__ h0hi, short* __restrict__ h0lo,
    short* __restrict__ h1hi, short* __restrict__ h1lo,
    float* __restrict__ c0, float* __restrict__ c1,
    const short* __restrict__ Wf, const float* __restrict__ biasF,
    const int* __restrict__ slen, int t)
{
  __shared__ short Bs[2 * 16384];
  const int layer = blockIdx.z;
  const int step  = t - layer;
  if (step < 0 || step >= 256) return;
  const int cur = step & 1;
  const int cb = blockIdx.x, rb = blockIdx.y;
  const size_t BH = (size_t)256 * 512;

  const float* a0f; const short* a0hi; const short* a0lo; long long sA0;
  const short* a1hi; const short* a1lo;
  float* cbuf; const short* hinhi; const short* hinlo;
  short* houthi; short* houtlo;
  const short* Wfl; const float* bfl;
  if (layer == 0) {
    // seq is [B, T, D]: batch-row stride = T*D = 131072 (round-3 fix).
    a0f = seq + (size_t)step * 512; a0hi = nullptr; a0lo = nullptr; sA0 = 131072;
    a1hi = h0hi + (size_t)cur * BH; a1lo = h0lo + (size_t)cur * BH;
    hinhi = a1hi; hinlo = a1lo;
    houthi = h0hi + (size_t)(cur ^ 1) * BH; houtlo = h0lo + (size_t)(cur ^ 1) * BH;
    cbuf = c0; Wfl = Wf; bfl = biasF;
  } else {
    a0f = nullptr;
    a0hi = h0hi + (size_t)(cur ^ 1) * BH; a0lo = h0lo + (size_t)(cur ^ 1) * BH;
    sA0 = 512;
    a1hi = h1hi + (size_t)cur * BH; a1lo = h1lo + (size_t)cur * BH;
    hinhi = a1hi; hinlo = a1lo;
    houthi = h1hi + (size_t)(cur ^ 1) * BH; houtlo = h1lo + (size_t)(cur ^ 1) * BH;
    cbuf = c1;
    Wfl = Wf + (size_t)4 * 2048 * 2048;            // layer1 weight base (shorts)
    bfl = biasF + 4 * 2048;
  }
  const short* Wfe = Wfl + ((size_t)rb * 2048 + (size_t)cb * 64) * 2048;
  gemm_body<0>(Bs, a0f, a0hi, a0lo, sA0, a1hi, a1lo, 512, 512, Wfe, bfl,
               2048, 1024, rb, cb, rb * 64, cbuf, hinhi, hinlo,
               houthi, houtlo, slen, step, nullptr, nullptr, nullptr);
}

template<int EPI>
__global__ __launch_bounds__(256) void head_gemm(
    const short* __restrict__ a0hi, const short* __restrict__ a0lo, long long sA0,
    const short* __restrict__ a1hi, const short* __restrict__ a1lo, long long sA1,
    int kSplit,
    const short* __restrict__ Wf, const float* __restrict__ bias,
    int N, int K,
    short* __restrict__ outhi, short* __restrict__ outlo, float* __restrict__ outf)
{
  __shared__ short Bs[2 * 16384];
  const int cb = blockIdx.x, rb = blockIdx.y;
  const short* Wfe = Wf + ((size_t)rb * N + (size_t)cb * 64) * 2 * K;
  gemm_body<EPI>(Bs, nullptr, a0hi, a0lo, sA0, a1hi, a1lo, sA1, kSplit, Wfe,
                 bias, N, K, rb, cb, rb * 64,
                 nullptr, nullptr, nullptr, nullptr, nullptr, nullptr, 0,
                 outhi, outlo, outf);
}

// ---------------------------------------------------------------------------
// Prep kernels: fold alpha/gamma into per-ensemble hi/lo bf16 weights.
// Wf[le][c'][plane][k]; c' = ublk*64 + gate*16 + j.
// ---------------------------------------------------------------------------
__global__ __launch_bounds__(256) void fold_lstm(
    const float* __restrict__ W, const float* __restrict__ U,
    const float* __restrict__ al, const float* __restrict__ ral,
    const float* __restrict__ ga, const float* __restrict__ rga,
    short* __restrict__ Wf)
{
  __shared__ float T[64][65];
  const int tid = threadIdx.x;
  const int kb = blockIdx.x * 64;   // 16 blocks over K=1024 (W 512 | U 512)
  const int cb = blockIdx.y;        // ublk, 32
  const int le = blockIdx.z;        // l*4+e, 8
  const int l  = le >> 2;
  const int kl = tid >> 2;
  const int g  = tid & 3;
  const int k  = kb + kl;
  const bool isW = k < 512;
  const int kk = isW ? k : k - 512;
  const float* src = (isW ? W : U) + ((size_t)l * 512 + kk) * 2048;
  const float  a   = (isW ? al : ral)[(size_t)le * 512 + kk];
  const float* gam = (isW ? ga : rga) + (size_t)le * 2048;
  const int colBase = g * 512 + cb * 16;
  const float4* s4 = reinterpret_cast<const float4*>(src + colBase);
  const float4* g4 = reinterpret_cast<const float4*>(gam + colBase);
  #pragma unroll
  for (int q = 0; q < 4; ++q) {
    float4 v = s4[q], gv = g4[q];
    T[kl][g * 16 + q * 4 + 0] = v.x * a * gv.x;
    T[kl][g * 16 + q * 4 + 1] = v.y * a * gv.y;
    T[kl][g * 16 + q * 4 + 2] = v.z * a * gv.z;
    T[kl][g * 16 + q * 4 + 3] = v.w * a * gv.w;
  }
  __syncthreads();
  const int cl = tid >> 2, kq0 = (tid & 3) * 16;
  alignas(16) short tH[16], tL[16];
  #pragma unroll
  for (int q = 0; q < 16; ++q) {
    short hh, hl; split2(T[kq0 + q][cl], hh, hl);
    tH[q] = hh; tL[q] = hl;
  }
  size_t dst = ((size_t)le * 2048 + cb * 64 + cl) * 2048 + kb + kq0;
  *reinterpret_cast<s16x8*>(Wf + dst)          = *reinterpret_cast<s16x8*>(tH);
  *reinterpret_cast<s16x8*>(Wf + dst + 8)      = *reinterpret_cast<s16x8*>(tH + 8);
  *reinterpret_cast<s16x8*>(Wf + dst + 1024)   = *reinterpret_cast<s16x8*>(tL);
  *reinterpret_cast<s16x8*>(Wf + dst + 1032)   = *reinterpret_cast<s16x8*>(tL + 8);
}

// Head: dst[e][col][plane][k] = src[k][col]*alpha[e][k]*gamma[e][col]
__global__ __launch_bounds__(256) void fold_plain(
    const float* __restrict__ src, const float* __restrict__ al,
    const float* __restrict__ ga, short* __restrict__ dst, int N, int K)
{
  __shared__ float T[64][65];
  const int tid = threadIdx.x;
  const int kb = blockIdx.x * 64;
  const int nb = blockIdx.y;
  const int e  = blockIdx.z;
  const int kl = tid >> 2;
  const int c0 = (tid & 3) * 16;
  const int k  = kb + kl;
  const float a = al[(size_t)e * K + k];
  const int colBase = nb * 64 + c0;
  const float4* s4 = reinterpret_cast<const float4*>(src + (size_t)k * N + colBase);
  const float4* g4 = reinterpret_cast<const float4*>(ga + (size_t)e * N + colBase);
  #pragma unroll
  for (int q = 0; q < 4; ++q) {
    float4 v = s4[q], gv = g4[q];
    T[kl][c0 + q * 4 + 0] = v.x * a * gv.x;
    T[kl][c0 + q * 4 + 1] = v.y * a * gv.y;
    T[kl][c0 + q * 4 + 2] = v.z * a * gv.z;
    T[kl][c0 + q * 4 + 3] = v.w * a * gv.w;
  }
  __syncthreads();
  const int cl = tid >> 2, kq0 = (tid & 3) * 16;
  alignas(16) short tH[16], tL[16];
  #pragma unroll
  for (int q = 0; q < 16; ++q) {
    short hh, hl; split2(T[kq0 + q][cl], hh, hl);
    tH[q] = hh; tL[q] = hl;
  }
  size_t d = ((size_t)e * N + nb * 64 + cl) * 2 * K + kb + kq0;
  *reinterpret_cast<s16x8*>(dst + d)         = *reinterpret_cast<s16x8*>(tH);
  *reinterpret_cast<s16x8*>(dst + d + 8)     = *reinterpret_cast<s16x8*>(tH + 8);
  *reinterpret_cast<s16x8*>(dst + d + K)     = *reinterpret_cast<s16x8*>(tL);
  *reinterpret_cast<s16x8*>(dst + d + K + 8) = *reinterpret_cast<s16x8*>(tL + 8);
}

__global__ void fold_bias_lstm(const float* __restrict__ b, float* __restrict__ bf) {
  int idx = blockIdx.x * 256 + threadIdx.x;          // 16384
  int cp = idx & 2047, le = idx >> 11;
  int ublk = cp >> 6, g = (cp >> 4) & 3, j = cp & 15;
  bf[idx] = b[(size_t)le * 2048 + g * 512 + ublk * 16 + j];
}

__global__ void cvt_split(const float* __restrict__ s,
                          short* __restrict__ hi, short* __restrict__ lo, int n) {
  int i = blockIdx.x * blockDim.x + threadIdx.x;
  if (i < n) { short h, l; split2(s[i], h, l); hi[i] = h; lo[i] = l; }
}

__global__ void zero_ws(float4* p, int n) {
  int i = blockIdx.x * blockDim.x + threadIdx.x;
  if (i < n) p[i] = make_float4(0.f, 0.f, 0.f, 0.f);
}

// ---------------------------------------------------------------------------
// workspace layout (bytes)
// ---------------------------------------------------------------------------
constexpr size_t OFF_WF    = 0;                        // 2*4*2048*2*1024*2 = 67108864
constexpr size_t OFF_WHID  = 67108864;                 // 4*256*2*768*2     = 3145728
constexpr size_t OFF_WOUT  = OFF_WHID + 3145728;       // 4*64*2*256*2      = 262144
constexpr size_t OFF_BIASF = OFF_WOUT + 262144;        // 16384*4           = 65536
constexpr size_t OFF_CTXH  = OFF_BIASF + 65536;        // 65536*2           = 131072
constexpr size_t OFF_CTXL  = OFF_CTXH + 131072;        // 131072
constexpr size_t OFF_H0HI  = OFF_CTXL + 131072;        // 2*256*512*2       = 524288
constexpr size_t OFF_H0LO  = OFF_H0HI + 524288;
constexpr size_t OFF_H1HI  = OFF_H0LO + 524288;
constexpr size_t OFF_H1LO  = OFF_H1HI + 524288;
constexpr size_t OFF_C0    = OFF_H1LO + 524288;        // 256*512*4         = 524288
constexpr size_t OFF_C1    = OFF_C0 + 524288;
constexpr size_t OFF_HIDH  = OFF_C1 + 524288;          // 256*256*2         = 131072
constexpr size_t OFF_HIDL  = OFF_HIDH + 131072;
// zero region: H0HI..C1 inclusive = 6*524288 = 3145728 bytes

extern "C" void kernel_launch(void* const* d_in, const int* in_sizes, int n_in,
                              void* d_out, int out_size, void* d_ws, size_t ws_size,
                              hipStream_t stream) {
  (void)in_sizes; (void)n_in; (void)out_size; (void)ws_size;
  const float* seq  = (const float*)d_in[0];
  const float* ctx  = (const float*)d_in[1];
  const int*   slen = (const int*)d_in[2];
  const float* lW   = (const float*)d_in[3];
  const float* lU   = (const float*)d_in[4];
  const float* lb   = (const float*)d_in[5];
  const float* lal  = (const float*)d_in[6];
  const float* lga  = (const float*)d_in[7];
  const float* lral = (const float*)d_in[8];
  const float* lrga = (const float*)d_in[9];
  const float* hW   = (const float*)d_in[10];
  const float* hb   = (const float*)d_in[11];
  const float* hal  = (const float*)d_in[12];
  const float* hga  = (const float*)d_in[13];
  const float* oW   = (const float*)d_in[14];
  const float* ob   = (const float*)d_in[15];
  const float* oal  = (const float*)d_in[16];
  const float* oga  = (const float*)d_in[17];

  char* ws = (char*)d_ws;
  short* Wf    = (short*)(ws + OFF_WF);
  short* Whid  = (short*)(ws + OFF_WHID);
  short* Wout  = (short*)(ws + OFF_WOUT);
  float* biasF = (float*)(ws + OFF_BIASF);
  short* ctxhi = (short*)(ws + OFF_CTXH);
  short* ctxlo = (short*)(ws + OFF_CTXL);
  short* h0hi  = (short*)(ws + OFF_H0HI);
  short* h0lo  = (short*)(ws + OFF_H0LO);
  short* h1hi  = (short*)(ws + OFF_H1HI);
  short* h1lo  = (short*)(ws + OFF_H1LO);
  float* c0    = (float*)(ws + OFF_C0);
  float* c1    = (float*)(ws + OFF_C1);
  short* hidhi = (short*)(ws + OFF_HIDH);
  short* hidlo = (short*)(ws + OFF_HIDL);

  // prep (every call: deterministic, no caching)
  fold_lstm<<<dim3(16, 32, 8), 256, 0, stream>>>(lW, lU, lal, lral, lga, lrga, Wf);
  fold_plain<<<dim3(12, 4, 4), 256, 0, stream>>>(hW, hal, hga, Whid, 256, 768);
  fold_plain<<<dim3(4, 1, 4), 256, 0, stream>>>(oW, oal, oga, Wout, 64, 256);
  fold_bias_lstm<<<64, 256, 0, stream>>>(lb, biasF);
  cvt_split<<<256, 256, 0, stream>>>(ctx, ctxhi, ctxlo, 65536);
  zero_ws<<<768, 256, 0, stream>>>((float4*)(ws + OFF_H0HI), 3145728 / 16);

  // recurrence: 257 phases (layer pipeline)
  for (int t = 0; t <= 256; ++t) {
    lstm_phase<<<dim3(32, 4, 2), 256, 0, stream>>>(seq, h0hi, h0lo, h1hi, h1lo,
                                                   c0, c1, Wf, biasF, slen, t);
  }

  // head: hidden = relu6(((h1,ctx)*a)@hid_W*g + b) ; out = ((hid*a)@out_W*g + b)
  head_gemm<1><<<dim3(4, 4), 256, 0, stream>>>(
      h1hi /* final state in buf0 */, h1lo, 512,
      ctxhi, ctxlo, 256, 512,
      Whid, hb, 256, 768, hidhi, hidlo, nullptr);
  head_gemm<2><<<dim3(1, 4), 256, 0, stream>>>(
      hidhi, hidlo, 256,
      nullptr, nullptr, 0, 256,
      Wout, ob, 64, 256,
      nullptr, nullptr, (float*)d_out);
}